// Round 4
// baseline (259.659 us; speedup 1.0000x reference)
//
#include <hip/hip_runtime.h>

#define NN 6144
#define SHIFTC (12.0f*1.4426950408889634f)
#define LOG2E 1.4426950408889634f

typedef float f32x4 __attribute__((ext_vector_type(4)));
typedef short short8 __attribute__((ext_vector_type(8)));
typedef int   i32x4 __attribute__((ext_vector_type(4)));
typedef unsigned int u32x4 __attribute__((ext_vector_type(4)));

__device__ __forceinline__ float bf2f(unsigned short u){
  return __uint_as_float(((unsigned int)u)<<16);
}
__device__ __forceinline__ unsigned short f2bf(float f){
  unsigned int x = __float_as_uint(f);
  x += 0x7fffu + ((x>>16)&1u);   // RNE
  return (unsigned short)(x>>16);
}

// ---- kernel 1: WhT bf16 [256][NN] = (x @ W)^T ----
__global__ __launch_bounds__(256) void k_gemm(const float* __restrict__ x,
                                              const float* __restrict__ W,
                                              unsigned short* __restrict__ wht){
  __shared__ float sx[16*256];
  const int t = threadIdx.x;
  const int i0 = blockIdx.x * 16;
  {
    const int r = t >> 4, kc = t & 15;
    const float* src = x + (size_t)(i0 + r)*256 + kc*16;
    float* dst = sx + r*256 + kc*16;
#pragma unroll
    for (int q = 0; q < 4; ++q)
      *reinterpret_cast<f32x4*>(dst + 4*q) = *reinterpret_cast<const f32x4*>(src + 4*q);
  }
  __syncthreads();
  float acc[16];
#pragma unroll
  for (int r = 0; r < 16; ++r) acc[r] = 0.f;
  for (int k = 0; k < 256; k += 4) {
    const float w0 = W[(size_t)(k+0)*256 + t];
    const float w1 = W[(size_t)(k+1)*256 + t];
    const float w2 = W[(size_t)(k+2)*256 + t];
    const float w3 = W[(size_t)(k+3)*256 + t];
#pragma unroll
    for (int r = 0; r < 16; ++r) {
      f32x4 xv = *reinterpret_cast<const f32x4*>(sx + r*256 + k);
      acc[r] = fmaf(xv.x, w0, acc[r]);
      acc[r] = fmaf(xv.y, w1, acc[r]);
      acc[r] = fmaf(xv.z, w2, acc[r]);
      acc[r] = fmaf(xv.w, w3, acc[r]);
    }
  }
  alignas(16) unsigned short buf[16];
#pragma unroll
  for (int r = 0; r < 16; ++r) buf[r] = f2bf(acc[r]);
  unsigned short* dst = wht + (size_t)t*NN + i0;
  *reinterpret_cast<uint4*>(dst)     = *reinterpret_cast<const uint4*>(buf);
  *reinterpret_cast<uint4*>(dst + 8) = *reinterpret_cast<const uint4*>(buf + 8);
}

// ---- kernel 2: per-node score factors ----
__global__ __launch_bounds__(256) void k_f(const unsigned short* __restrict__ wht,
                                           const float* __restrict__ a,
                                           float* __restrict__ fs2,
                                           float* __restrict__ edp,
                                           float* __restrict__ edn){
  __shared__ unsigned short sw[256*64];
  const int t = threadIdx.x;
  const int i0 = blockIdx.x * 64;
  {
    const unsigned short* src = wht + (size_t)t*NN + i0;
    unsigned short* dst = sw + t*64;
#pragma unroll
    for (int q = 0; q < 8; ++q)
      *reinterpret_cast<uint4*>(dst + q*8) = *reinterpret_cast<const uint4*>(src + q*8);
  }
  __syncthreads();
  const int ii = t & 63, h = t >> 6;
  float s_ = 0.f, d_ = 0.f;
#pragma unroll 16
  for (int d = 0; d < 64; ++d) {
    const float v = bf2f(sw[(h*64 + d)*64 + ii]);
    s_ = fmaf(v, a[d],      s_);
    d_ = fmaf(v, a[64 + d], d_);
  }
  const float fs2v = s_ * LOG2E;
  const float fd2v = d_ * LOG2E;
  fs2[(size_t)h*NN + i0 + ii] = fs2v;
  edp[(size_t)h*NN + i0 + ii] = exp2f(fd2v - SHIFTC);
  edn[(size_t)h*NN + i0 + ii] = exp2f(0.2f * fd2v);
}

// ---- kernel 3: fused masked-softmax attention, T14 async-stage prefetch ----
__global__ __launch_bounds__(256) void k_attn(const int* __restrict__ adj,
                                              const unsigned short* __restrict__ wht,
                                              const float* __restrict__ fs2,
                                              const float* __restrict__ edp,
                                              const float* __restrict__ edn,
                                              float* __restrict__ apart,
                                              float* __restrict__ lpart,
                                              int nsteps){
  __shared__ unsigned short swht[256*72];   // [c][64 j] padded to 72
  __shared__ unsigned int   smask[64*2];    // 64 rows x 64 bits
  __shared__ float          sedp[256];
  __shared__ float          sedn[256];
  const int t  = threadIdx.x;
  const int w  = t >> 6, l = t & 63, lr = l & 15, hi = l >> 4;
  const int it = blockIdx.x % 96;
  const int js = blockIdx.x / 96;
  const int i0 = it * 64;
  const int jbase = js * nsteps * 64;
  const int i_row = i0 + w*16 + lr;

  // base pointers for this thread's staging slice (advance by 64 j per step)
  const unsigned short* wsrc = wht + (size_t)t*NN + jbase;
  const int*   asrc = adj + (size_t)(i0 + (t>>2))*NN + jbase + (t&3)*16;
  const float* pesrc = edp + (size_t)(t>>6)*NN + jbase + (t&63);
  const float* nesrc = edn + (size_t)(t>>6)*NN + jbase + (t&63);

  float TP[4], EiN[4];
#pragma unroll
  for (int h = 0; h < 4; ++h) {
    const float f = fs2[(size_t)h*NN + i_row];
    TP[h]  = exp2f(-f - SHIFTC);
    EiN[h] = exp2f(-0.8f*f - SHIFTC);
  }
  f32x4 acc[16];
#pragma unroll
  for (int q = 0; q < 16; ++q) acc[q] = (f32x4){0.f,0.f,0.f,0.f};
  float ls[4] = {0.f,0.f,0.f,0.f};

  // ---- prologue: stage step 0 ----
  {
    uint4 wv[8]; i32x4 aj[4];
#pragma unroll
    for (int q = 0; q < 8; ++q) wv[q] = *reinterpret_cast<const uint4*>(wsrc + q*8);
#pragma unroll
    for (int q = 0; q < 4; ++q)
      aj[q] = __builtin_nontemporal_load(reinterpret_cast<const i32x4*>(asrc + q*4));
    const float pe = *pesrc, ne = *nesrc;
    unsigned short* dst = swht + t*72;
#pragma unroll
    for (int q = 0; q < 8; ++q) *reinterpret_cast<uint4*>(dst + q*8) = wv[q];
    unsigned int bits = 0u;
#pragma unroll
    for (int q = 0; q < 4; ++q) {
      bits |= (aj[q].x != 0 ? 1u : 0u) << (q*4 + 0);
      bits |= (aj[q].y != 0 ? 1u : 0u) << (q*4 + 1);
      bits |= (aj[q].z != 0 ? 1u : 0u) << (q*4 + 2);
      bits |= (aj[q].w != 0 ? 1u : 0u) << (q*4 + 3);
    }
    reinterpret_cast<unsigned short*>(smask)[(t>>2)*4 + (t&3)] = (unsigned short)bits;
    sedp[t] = pe; sedn[t] = ne;
    __syncthreads();
  }

  for (int st = 0; st < nsteps; ++st) {
    const bool pf = (st + 1) < nsteps;   // block-uniform
    // ---- issue next step's loads into registers (latency hides under compute) ----
    uint4 wv[8]; i32x4 aj[4]; float pe = 0.f, ne = 0.f;
    if (pf) {
      const int o = (st + 1) * 64;
#pragma unroll
      for (int q = 0; q < 4; ++q)
        aj[q] = __builtin_nontemporal_load(reinterpret_cast<const i32x4*>(asrc + o + q*4));
#pragma unroll
      for (int q = 0; q < 8; ++q) wv[q] = *reinterpret_cast<const uint4*>(wsrc + o + q*8);
      pe = pesrc[o]; ne = nesrc[o];
    }

    // ---- compute current step from LDS ----
    const unsigned int m0 = smask[(w*16 + lr)*2 + 0];
    const unsigned int m1 = smask[(w*16 + lr)*2 + 1];
    float maskf[16];
#pragma unroll
    for (int e = 0; e < 8; ++e) {
      maskf[e]     = ((m0 >> (8*hi + e)) & 1u) ? 1.f : 0.f;
      maskf[8 + e] = ((m1 >> (8*hi + e)) & 1u) ? 1.f : 0.f;
    }
#pragma unroll
    for (int h = 0; h < 4; ++h) {
      const float TPh = TP[h], EiNh = EiN[h];
      const f32x4 ep0 = *reinterpret_cast<const f32x4*>(&sedp[h*64 + 8*hi + 0]);
      const f32x4 ep1 = *reinterpret_cast<const f32x4*>(&sedp[h*64 + 8*hi + 4]);
      const f32x4 ep2 = *reinterpret_cast<const f32x4*>(&sedp[h*64 + 32 + 8*hi + 0]);
      const f32x4 ep3 = *reinterpret_cast<const f32x4*>(&sedp[h*64 + 32 + 8*hi + 4]);
      const f32x4 en0 = *reinterpret_cast<const f32x4*>(&sedn[h*64 + 8*hi + 0]);
      const f32x4 en1 = *reinterpret_cast<const f32x4*>(&sedn[h*64 + 8*hi + 4]);
      const f32x4 en2 = *reinterpret_cast<const f32x4*>(&sedn[h*64 + 32 + 8*hi + 0]);
      const f32x4 en3 = *reinterpret_cast<const f32x4*>(&sedn[h*64 + 32 + 8*hi + 4]);
      float p[16];
#pragma unroll
      for (int e = 0; e < 4; ++e) {
        p[e]      = maskf[e]      * (ep0[e] > TPh ? ep0[e] : EiNh * en0[e]);
        p[4 + e]  = maskf[4 + e]  * (ep1[e] > TPh ? ep1[e] : EiNh * en1[e]);
        p[8 + e]  = maskf[8 + e]  * (ep2[e] > TPh ? ep2[e] : EiNh * en2[e]);
        p[12 + e] = maskf[12 + e] * (ep3[e] > TPh ? ep3[e] : EiNh * en3[e]);
      }
      float lsh = 0.f;
#pragma unroll
      for (int e = 0; e < 16; ++e) lsh += p[e];
      ls[h] += lsh;
      int4 aw0, aw1;
      asm("v_cvt_pk_bf16_f32 %0, %1, %2" : "=v"(aw0.x) : "v"(p[0]),  "v"(p[1]));
      asm("v_cvt_pk_bf16_f32 %0, %1, %2" : "=v"(aw0.y) : "v"(p[2]),  "v"(p[3]));
      asm("v_cvt_pk_bf16_f32 %0, %1, %2" : "=v"(aw0.z) : "v"(p[4]),  "v"(p[5]));
      asm("v_cvt_pk_bf16_f32 %0, %1, %2" : "=v"(aw0.w) : "v"(p[6]),  "v"(p[7]));
      asm("v_cvt_pk_bf16_f32 %0, %1, %2" : "=v"(aw1.x) : "v"(p[8]),  "v"(p[9]));
      asm("v_cvt_pk_bf16_f32 %0, %1, %2" : "=v"(aw1.y) : "v"(p[10]), "v"(p[11]));
      asm("v_cvt_pk_bf16_f32 %0, %1, %2" : "=v"(aw1.z) : "v"(p[12]), "v"(p[13]));
      asm("v_cvt_pk_bf16_f32 %0, %1, %2" : "=v"(aw1.w) : "v"(p[14]), "v"(p[15]));
      const short8 af0 = __builtin_bit_cast(short8, aw0);
      const short8 af1 = __builtin_bit_cast(short8, aw1);
#pragma unroll
      for (int nc = 0; nc < 4; ++nc) {
        const unsigned short* bp = swht + (size_t)(h*64 + nc*16 + lr)*72 + 8*hi;
        const short8 b0 = *reinterpret_cast<const short8*>(bp);
        const short8 b1 = *reinterpret_cast<const short8*>(bp + 32);
        acc[h*4 + nc] = __builtin_amdgcn_mfma_f32_16x16x32_bf16(af0, b0, acc[h*4 + nc], 0, 0, 0);
        acc[h*4 + nc] = __builtin_amdgcn_mfma_f32_16x16x32_bf16(af1, b1, acc[h*4 + nc], 0, 0, 0);
      }
    }

    // ---- commit prefetched tile to LDS ----
    if (pf) {
      __syncthreads();   // all waves done reading current LDS tile
      unsigned short* dst = swht + t*72;
#pragma unroll
      for (int q = 0; q < 8; ++q) *reinterpret_cast<uint4*>(dst + q*8) = wv[q];
      unsigned int bits = 0u;
#pragma unroll
      for (int q = 0; q < 4; ++q) {
        bits |= (aj[q].x != 0 ? 1u : 0u) << (q*4 + 0);
        bits |= (aj[q].y != 0 ? 1u : 0u) << (q*4 + 1);
        bits |= (aj[q].z != 0 ? 1u : 0u) << (q*4 + 2);
        bits |= (aj[q].w != 0 ? 1u : 0u) << (q*4 + 3);
      }
      reinterpret_cast<unsigned short*>(smask)[(t>>2)*4 + (t&3)] = (unsigned short)bits;
      sedp[t] = pe; sedn[t] = ne;
      __syncthreads();   // next tile ready
    }
  }

  // reduce denominator across the 4 k-groups (lanes sharing lr)
#pragma unroll
  for (int h = 0; h < 4; ++h) {
    float v = ls[h];
    v += __shfl_xor(v, 16, 64);
    v += __shfl_xor(v, 32, 64);
    ls[h] = v;
  }
  if (hi == 0) {
#pragma unroll
    for (int h = 0; h < 4; ++h)
      lpart[((size_t)js*4 + h)*NN + i_row] = ls[h];
  }
  // C/D layout: col = lane&15, row = 4*(lane>>4)+reg   [m89-verified]
#pragma unroll
  for (int h = 0; h < 4; ++h)
#pragma unroll
    for (int nc = 0; nc < 4; ++nc)
#pragma unroll
      for (int rg = 0; rg < 4; ++rg) {
        const int irow = i0 + w*16 + 4*hi + rg;
        const int col  = h*64 + nc*16 + lr;
        apart[((size_t)js*NN + irow)*256 + col] = acc[h*4 + nc][rg];
      }
}

// ---- kernel 4: combine partials ----
__global__ __launch_bounds__(256) void k_comb(const float* __restrict__ apart,
                                              const float* __restrict__ lpart,
                                              float* __restrict__ out,
                                              int jsplit){
  const int idx = blockIdx.x * 256 + threadIdx.x;
  const int i = idx >> 8, c = idx & 255, h = c >> 6;
  float num = 0.f, den = 0.f;
  for (int s = 0; s < jsplit; ++s) {
    num += apart[((size_t)s*NN + i)*256 + c];
    den += lpart[((size_t)s*4 + h)*NN + i];
  }
  out[idx] = (den > 0.f) ? (num / den) : 0.f;
}

extern "C" void kernel_launch(void* const* d_in, const int* in_sizes, int n_in,
                              void* d_out, int out_size, void* d_ws, size_t ws_size,
                              hipStream_t stream) {
  const float* x   = (const float*)d_in[0];
  const int*   adj = (const int*)d_in[1];
  const float* W   = (const float*)d_in[2];
  const float* a   = (const float*)d_in[3];
  float* out = (float*)d_out;
  char* ws = (char*)d_ws;

  size_t off = 0;
  unsigned short* wht = (unsigned short*)(ws + off); off += (size_t)256*NN*2;
  float* fs2 = (float*)(ws + off); off += (size_t)4*NN*4;
  float* edp = (float*)(ws + off); off += (size_t)4*NN*4;
  float* edn = (float*)(ws + off); off += (size_t)4*NN*4;

  int jsplit = 8;
  while (jsplit > 1 &&
         off + (size_t)jsplit*4*NN*4 + (size_t)jsplit*NN*256*4 > ws_size)
    jsplit >>= 1;

  float* lpart = (float*)(ws + off); off += (size_t)jsplit*4*NN*4;
  float* apart = (float*)(ws + off);

  const int nsteps = NN / (jsplit * 64);

  k_gemm<<<dim3(NN/16), dim3(256), 0, stream>>>(x, W, wht);
  k_f   <<<dim3(NN/64), dim3(256), 0, stream>>>(wht, a, fs2, edp, edn);
  k_attn<<<dim3((NN/64)*jsplit), dim3(256), 0, stream>>>(adj, wht, fs2, edp, edn, apart, lpart, nsteps);
  k_comb<<<dim3((out_size + 255)/256), dim3(256), 0, stream>>>(apart, lpart, out, jsplit);
}

// Round 8
// 138.620 us; speedup vs baseline: 1.8732x; 1.8732x over previous
//
#include <hip/hip_runtime.h>

#define NN 6144
#define SHIFTC (12.0f*1.4426950408889634f)
#define LOG2E 1.4426950408889634f

typedef float f32x4 __attribute__((ext_vector_type(4)));
typedef short short8 __attribute__((ext_vector_type(8)));
typedef int   i32x4 __attribute__((ext_vector_type(4)));

__device__ __forceinline__ float bf2f(unsigned short u){
  return __uint_as_float(((unsigned int)u)<<16);
}
__device__ __forceinline__ unsigned short f2bf(float f){
  unsigned int x = __float_as_uint(f);
  x += 0x7fffu + ((x>>16)&1u);   // RNE
  return (unsigned short)(x>>16);
}

// ---- kernel 1: WhT bf16 [256][NN] = (x @ W)^T ----
__global__ __launch_bounds__(256) void k_gemm(const float* __restrict__ x,
                                              const float* __restrict__ W,
                                              unsigned short* __restrict__ wht){
  __shared__ float sx[16*256];
  const int t = threadIdx.x;
  const int i0 = blockIdx.x * 16;
  {
    const int r = t >> 4, kc = t & 15;
    const float* src = x + (size_t)(i0 + r)*256 + kc*16;
    float* dst = sx + r*256 + kc*16;
#pragma unroll
    for (int q = 0; q < 4; ++q)
      *reinterpret_cast<f32x4*>(dst + 4*q) = *reinterpret_cast<const f32x4*>(src + 4*q);
  }
  __syncthreads();
  float acc[16];
#pragma unroll
  for (int r = 0; r < 16; ++r) acc[r] = 0.f;
  for (int k = 0; k < 256; k += 4) {
    const float w0 = W[(size_t)(k+0)*256 + t];
    const float w1 = W[(size_t)(k+1)*256 + t];
    const float w2 = W[(size_t)(k+2)*256 + t];
    const float w3 = W[(size_t)(k+3)*256 + t];
#pragma unroll
    for (int r = 0; r < 16; ++r) {
      f32x4 xv = *reinterpret_cast<const f32x4*>(sx + r*256 + k);
      acc[r] = fmaf(xv.x, w0, acc[r]);
      acc[r] = fmaf(xv.y, w1, acc[r]);
      acc[r] = fmaf(xv.z, w2, acc[r]);
      acc[r] = fmaf(xv.w, w3, acc[r]);
    }
  }
  alignas(16) unsigned short buf[16];
#pragma unroll
  for (int r = 0; r < 16; ++r) buf[r] = f2bf(acc[r]);
  unsigned short* dst = wht + (size_t)t*NN + i0;
  *reinterpret_cast<uint4*>(dst)     = *reinterpret_cast<const uint4*>(buf);
  *reinterpret_cast<uint4*>(dst + 8) = *reinterpret_cast<const uint4*>(buf + 8);
}

// ---- kernel 2: per-node score factors ----
__global__ __launch_bounds__(256) void k_f(const unsigned short* __restrict__ wht,
                                           const float* __restrict__ a,
                                           float* __restrict__ fs2,
                                           float* __restrict__ edp,
                                           float* __restrict__ edn){
  __shared__ unsigned short sw[256*64];
  const int t = threadIdx.x;
  const int i0 = blockIdx.x * 64;
  {
    const unsigned short* src = wht + (size_t)t*NN + i0;
    unsigned short* dst = sw + t*64;
#pragma unroll
    for (int q = 0; q < 8; ++q)
      *reinterpret_cast<uint4*>(dst + q*8) = *reinterpret_cast<const uint4*>(src + q*8);
  }
  __syncthreads();
  const int ii = t & 63, h = t >> 6;
  float s_ = 0.f, d_ = 0.f;
#pragma unroll 16
  for (int d = 0; d < 64; ++d) {
    const float v = bf2f(sw[(h*64 + d)*64 + ii]);
    s_ = fmaf(v, a[d],      s_);
    d_ = fmaf(v, a[64 + d], d_);
  }
  const float fs2v = s_ * LOG2E;
  const float fd2v = d_ * LOG2E;
  fs2[(size_t)h*NN + i0 + ii] = fs2v;
  edp[(size_t)h*NN + i0 + ii] = exp2f(fd2v - SHIFTC);
  edn[(size_t)h*NN + i0 + ii] = exp2f(0.2f * fd2v);
}

// ---- kernel 3: fused masked-softmax attention (R2 + adj-only reg prefetch) ----
// grid: (96 i-tiles) x jsplit.  block: 256 = 4 waves, each wave owns 16 i-rows.
__global__ __launch_bounds__(256) void k_attn(const int* __restrict__ adj,
                                              const unsigned short* __restrict__ wht,
                                              const float* __restrict__ fs2,
                                              const float* __restrict__ edp,
                                              const float* __restrict__ edn,
                                              float* __restrict__ apart,
                                              float* __restrict__ lpart,
                                              int nsteps){
  __shared__ unsigned short swht[256*72];   // [c][64 j] padded to 72
  __shared__ unsigned int   smask[64*2];    // 64 rows x 64 bits
  __shared__ float          sedp[256];
  __shared__ float          sedn[256];
  const int t  = threadIdx.x;
  const int w  = t >> 6, l = t & 63, lr = l & 15, hi = l >> 4;
  const int it = blockIdx.x % 96;
  const int js = blockIdx.x / 96;
  const int i0 = it * 64;
  const int jbase = js * nsteps * 64;
  const int i_row = i0 + w*16 + lr;

  float TP[4], EiN[4];
#pragma unroll
  for (int h = 0; h < 4; ++h) {
    const float f = fs2[(size_t)h*NN + i_row];
    TP[h]  = exp2f(-f - SHIFTC);
    EiN[h] = exp2f(-0.8f*f - SHIFTC);
  }
  f32x4 acc[16];
#pragma unroll
  for (int q = 0; q < 16; ++q) acc[q] = (f32x4){0.f,0.f,0.f,0.f};
  float ls[4] = {0.f,0.f,0.f,0.f};

  // adj staging slice for this thread (same assignment as R2)
  const int r_ = t >> 2, ch_ = t & 3;
  const int* asrc = adj + (size_t)(i0 + r_)*NN + jbase + ch_*16;

  // prefetch step-0 adj into registers (16 VGPRs)
  i32x4 ajp[4];
#pragma unroll
  for (int q = 0; q < 4; ++q)
    ajp[q] = *reinterpret_cast<const i32x4*>(asrc + q*4);

  for (int st = 0; st < nsteps; ++st) {
    const int j0 = jbase + st*64;
    __syncthreads();
    { // stage WhT tile: thread t copies row c=t, 64 bf16 (128B)
      const unsigned short* src = wht + (size_t)t*NN + j0;
      unsigned short* dst = swht + t*72;
#pragma unroll
      for (int q = 0; q < 8; ++q)
        *reinterpret_cast<uint4*>(dst + q*8) = *reinterpret_cast<const uint4*>(src + q*8);
    }
    { // pack prefetched adj registers into smask bits
      unsigned int bits = 0u;
#pragma unroll
      for (int q = 0; q < 4; ++q) {
        bits |= (ajp[q].x != 0 ? 1u : 0u) << (q*4 + 0);
        bits |= (ajp[q].y != 0 ? 1u : 0u) << (q*4 + 1);
        bits |= (ajp[q].z != 0 ? 1u : 0u) << (q*4 + 2);
        bits |= (ajp[q].w != 0 ? 1u : 0u) << (q*4 + 3);
      }
      reinterpret_cast<unsigned short*>(smask)[r_*4 + ch_] = (unsigned short)bits;
    }
    { // stage edp/edn tiles (4 heads x 64 j)
      sedp[t] = edp[(size_t)(t >> 6)*NN + j0 + (t & 63)];
      sedn[t] = edn[(size_t)(t >> 6)*NN + j0 + (t & 63)];
    }
    __syncthreads();

    // issue next step's adj loads NOW — their ~900cy HBM latency hides
    // under the compute below; consumed at next iteration's staging.
    if (st + 1 < nsteps) {
      const int* an = asrc + (st + 1)*64;
#pragma unroll
      for (int q = 0; q < 4; ++q)
        ajp[q] = *reinterpret_cast<const i32x4*>(an + q*4);
    }

    const unsigned int m0 = smask[(w*16 + lr)*2 + 0];
    const unsigned int m1 = smask[(w*16 + lr)*2 + 1];
    float maskf[16];
#pragma unroll
    for (int e = 0; e < 8; ++e) {
      maskf[e]     = ((m0 >> (8*hi + e)) & 1u) ? 1.f : 0.f;
      maskf[8 + e] = ((m1 >> (8*hi + e)) & 1u) ? 1.f : 0.f;
    }
#pragma unroll
    for (int h = 0; h < 4; ++h) {
      const float TPh = TP[h], EiNh = EiN[h];
      const f32x4 ep0 = *reinterpret_cast<const f32x4*>(&sedp[h*64 + 8*hi + 0]);
      const f32x4 ep1 = *reinterpret_cast<const f32x4*>(&sedp[h*64 + 8*hi + 4]);
      const f32x4 ep2 = *reinterpret_cast<const f32x4*>(&sedp[h*64 + 32 + 8*hi + 0]);
      const f32x4 ep3 = *reinterpret_cast<const f32x4*>(&sedp[h*64 + 32 + 8*hi + 4]);
      const f32x4 en0 = *reinterpret_cast<const f32x4*>(&sedn[h*64 + 8*hi + 0]);
      const f32x4 en1 = *reinterpret_cast<const f32x4*>(&sedn[h*64 + 8*hi + 4]);
      const f32x4 en2 = *reinterpret_cast<const f32x4*>(&sedn[h*64 + 32 + 8*hi + 0]);
      const f32x4 en3 = *reinterpret_cast<const f32x4*>(&sedn[h*64 + 32 + 8*hi + 4]);
      float p[16];
#pragma unroll
      for (int e = 0; e < 4; ++e) {
        p[e]      = maskf[e]      * (ep0[e] > TPh ? ep0[e] : EiNh * en0[e]);
        p[4 + e]  = maskf[4 + e]  * (ep1[e] > TPh ? ep1[e] : EiNh * en1[e]);
        p[8 + e]  = maskf[8 + e]  * (ep2[e] > TPh ? ep2[e] : EiNh * en2[e]);
        p[12 + e] = maskf[12 + e] * (ep3[e] > TPh ? ep3[e] : EiNh * en3[e]);
      }
      float lsh = 0.f;
#pragma unroll
      for (int e = 0; e < 16; ++e) lsh += p[e];
      ls[h] += lsh;
      int4 aw0, aw1;
      asm("v_cvt_pk_bf16_f32 %0, %1, %2" : "=v"(aw0.x) : "v"(p[0]),  "v"(p[1]));
      asm("v_cvt_pk_bf16_f32 %0, %1, %2" : "=v"(aw0.y) : "v"(p[2]),  "v"(p[3]));
      asm("v_cvt_pk_bf16_f32 %0, %1, %2" : "=v"(aw0.z) : "v"(p[4]),  "v"(p[5]));
      asm("v_cvt_pk_bf16_f32 %0, %1, %2" : "=v"(aw0.w) : "v"(p[6]),  "v"(p[7]));
      asm("v_cvt_pk_bf16_f32 %0, %1, %2" : "=v"(aw1.x) : "v"(p[8]),  "v"(p[9]));
      asm("v_cvt_pk_bf16_f32 %0, %1, %2" : "=v"(aw1.y) : "v"(p[10]), "v"(p[11]));
      asm("v_cvt_pk_bf16_f32 %0, %1, %2" : "=v"(aw1.z) : "v"(p[12]), "v"(p[13]));
      asm("v_cvt_pk_bf16_f32 %0, %1, %2" : "=v"(aw1.w) : "v"(p[14]), "v"(p[15]));
      const short8 af0 = __builtin_bit_cast(short8, aw0);
      const short8 af1 = __builtin_bit_cast(short8, aw1);
#pragma unroll
      for (int nc = 0; nc < 4; ++nc) {
        const unsigned short* bp = swht + (size_t)(h*64 + nc*16 + lr)*72 + 8*hi;
        const short8 b0 = *reinterpret_cast<const short8*>(bp);
        const short8 b1 = *reinterpret_cast<const short8*>(bp + 32);
        acc[h*4 + nc] = __builtin_amdgcn_mfma_f32_16x16x32_bf16(af0, b0, acc[h*4 + nc], 0, 0, 0);
        acc[h*4 + nc] = __builtin_amdgcn_mfma_f32_16x16x32_bf16(af1, b1, acc[h*4 + nc], 0, 0, 0);
      }
    }
  }

  // reduce denominator across the 4 k-groups (lanes sharing lr)
#pragma unroll
  for (int h = 0; h < 4; ++h) {
    float v = ls[h];
    v += __shfl_xor(v, 16, 64);
    v += __shfl_xor(v, 32, 64);
    ls[h] = v;
  }
  if (hi == 0) {
#pragma unroll
    for (int h = 0; h < 4; ++h)
      lpart[((size_t)js*4 + h)*NN + i_row] = ls[h];
  }
  // C/D layout: col = lane&15, row = 4*(lane>>4)+reg   [m89-verified]
#pragma unroll
  for (int h = 0; h < 4; ++h)
#pragma unroll
    for (int nc = 0; nc < 4; ++nc)
#pragma unroll
      for (int rg = 0; rg < 4; ++rg) {
        const int irow = i0 + w*16 + 4*hi + rg;
        const int col  = h*64 + nc*16 + lr;
        apart[((size_t)js*NN + irow)*256 + col] = acc[h*4 + nc][rg];
      }
}

// ---- kernel 4: combine partials ----
__global__ __launch_bounds__(256) void k_comb(const float* __restrict__ apart,
                                              const float* __restrict__ lpart,
                                              float* __restrict__ out,
                                              int jsplit){
  const int idx = blockIdx.x * 256 + threadIdx.x;
  const int i = idx >> 8, c = idx & 255, h = c >> 6;
  float num = 0.f, den = 0.f;
  for (int s = 0; s < jsplit; ++s) {
    num += apart[((size_t)s*NN + i)*256 + c];
    den += lpart[((size_t)s*4 + h)*NN + i];
  }
  out[idx] = (den > 0.f) ? (num / den) : 0.f;
}

extern "C" void kernel_launch(void* const* d_in, const int* in_sizes, int n_in,
                              void* d_out, int out_size, void* d_ws, size_t ws_size,
                              hipStream_t stream) {
  const float* x   = (const float*)d_in[0];
  const int*   adj = (const int*)d_in[1];
  const float* W   = (const float*)d_in[2];
  const float* a   = (const float*)d_in[3];
  float* out = (float*)d_out;
  char* ws = (char*)d_ws;

  size_t off = 0;
  unsigned short* wht = (unsigned short*)(ws + off); off += (size_t)256*NN*2;
  float* fs2 = (float*)(ws + off); off += (size_t)4*NN*4;
  float* edp = (float*)(ws + off); off += (size_t)4*NN*4;
  float* edn = (float*)(ws + off); off += (size_t)4*NN*4;

  int jsplit = 8;
  while (jsplit > 1 &&
         off + (size_t)jsplit*4*NN*4 + (size_t)jsplit*NN*256*4 > ws_size)
    jsplit >>= 1;

  float* lpart = (float*)(ws + off); off += (size_t)jsplit*4*NN*4;
  float* apart = (float*)(ws + off);

  const int nsteps = NN / (jsplit * 64);

  k_gemm<<<dim3(NN/16), dim3(256), 0, stream>>>(x, W, wht);
  k_f   <<<dim3(NN/64), dim3(256), 0, stream>>>(wht, a, fs2, edp, edn);
  k_attn<<<dim3((NN/64)*jsplit), dim3(256), 0, stream>>>(adj, wht, fs2, edp, edn, apart, lpart, nsteps);
  k_comb<<<dim3((out_size + 255)/256), dim3(256), 0, stream>>>(apart, lpart, out, jsplit);
}

// Round 9
// 121.700 us; speedup vs baseline: 2.1336x; 1.1390x over previous
//
#include <hip/hip_runtime.h>

#define NN 6144
#define SHIFTC (12.0f*1.4426950408889634f)
#define LOG2E 1.4426950408889634f

typedef float f32x4 __attribute__((ext_vector_type(4)));
typedef short short8 __attribute__((ext_vector_type(8)));
typedef int   i32x4 __attribute__((ext_vector_type(4)));

__device__ __forceinline__ float bf2f(unsigned short u){
  return __uint_as_float(((unsigned int)u)<<16);
}
__device__ __forceinline__ unsigned short f2bf(float f){
  unsigned int x = __float_as_uint(f);
  x += 0x7fffu + ((x>>16)&1u);   // RNE
  return (unsigned short)(x>>16);
}

// ---- kernel 1: WhT bf16 [256][NN] = (x @ W)^T ----
__global__ __launch_bounds__(256) void k_gemm(const float* __restrict__ x,
                                              const float* __restrict__ W,
                                              unsigned short* __restrict__ wht){
  __shared__ float sx[16*256];
  const int t = threadIdx.x;
  const int i0 = blockIdx.x * 16;
  {
    const int r = t >> 4, kc = t & 15;
    const float* src = x + (size_t)(i0 + r)*256 + kc*16;
    float* dst = sx + r*256 + kc*16;
#pragma unroll
    for (int q = 0; q < 4; ++q)
      *reinterpret_cast<f32x4*>(dst + 4*q) = *reinterpret_cast<const f32x4*>(src + 4*q);
  }
  __syncthreads();
  float acc[16];
#pragma unroll
  for (int r = 0; r < 16; ++r) acc[r] = 0.f;
  for (int k = 0; k < 256; k += 4) {
    const float w0 = W[(size_t)(k+0)*256 + t];
    const float w1 = W[(size_t)(k+1)*256 + t];
    const float w2 = W[(size_t)(k+2)*256 + t];
    const float w3 = W[(size_t)(k+3)*256 + t];
#pragma unroll
    for (int r = 0; r < 16; ++r) {
      f32x4 xv = *reinterpret_cast<const f32x4*>(sx + r*256 + k);
      acc[r] = fmaf(xv.x, w0, acc[r]);
      acc[r] = fmaf(xv.y, w1, acc[r]);
      acc[r] = fmaf(xv.z, w2, acc[r]);
      acc[r] = fmaf(xv.w, w3, acc[r]);
    }
  }
  alignas(16) unsigned short buf[16];
#pragma unroll
  for (int r = 0; r < 16; ++r) buf[r] = f2bf(acc[r]);
  unsigned short* dst = wht + (size_t)t*NN + i0;
  *reinterpret_cast<uint4*>(dst)     = *reinterpret_cast<const uint4*>(buf);
  *reinterpret_cast<uint4*>(dst + 8) = *reinterpret_cast<const uint4*>(buf + 8);
}

// ---- kernel 2: per-node score factors ----
__global__ __launch_bounds__(256) void k_f(const unsigned short* __restrict__ wht,
                                           const float* __restrict__ a,
                                           float* __restrict__ fs2,
                                           float* __restrict__ edp,
                                           float* __restrict__ edn){
  __shared__ unsigned short sw[256*64];
  const int t = threadIdx.x;
  const int i0 = blockIdx.x * 64;
  {
    const unsigned short* src = wht + (size_t)t*NN + i0;
    unsigned short* dst = sw + t*64;
#pragma unroll
    for (int q = 0; q < 8; ++q)
      *reinterpret_cast<uint4*>(dst + q*8) = *reinterpret_cast<const uint4*>(src + q*8);
  }
  __syncthreads();
  const int ii = t & 63, h = t >> 6;
  float s_ = 0.f, d_ = 0.f;
#pragma unroll 16
  for (int d = 0; d < 64; ++d) {
    const float v = bf2f(sw[(h*64 + d)*64 + ii]);
    s_ = fmaf(v, a[d],      s_);
    d_ = fmaf(v, a[64 + d], d_);
  }
  const float fs2v = s_ * LOG2E;
  const float fd2v = d_ * LOG2E;
  fs2[(size_t)h*NN + i0 + ii] = fs2v;
  edp[(size_t)h*NN + i0 + ii] = exp2f(fd2v - SHIFTC);
  edn[(size_t)h*NN + i0 + ii] = exp2f(0.2f * fd2v);
}

// ---- kernel 3: fused masked-softmax attention, ONE HEAD per block ----
// grid: 4 heads x 96 i-tiles x jsplit.  h = (bid>>3)&3 so the 4 head-blocks
// of one (it,js) share an XCD (same bid%8) -> adj tile L2 reuse.
// block: 256 = 4 waves, each wave owns 16 i-rows.
__global__ __launch_bounds__(256) void k_attn(const int* __restrict__ adj,
                                              const unsigned short* __restrict__ wht,
                                              const float* __restrict__ fs2,
                                              const float* __restrict__ edp,
                                              const float* __restrict__ edn,
                                              float* __restrict__ apart,
                                              float* __restrict__ lpart,
                                              int nsteps){
  __shared__ unsigned short swht[64*72];    // [64 ch][64 j] padded to 72
  __shared__ unsigned int   smask[64*2];    // 64 rows x 64 bits
  __shared__ float          sedp[64];
  __shared__ float          sedn[64];
  const int t  = threadIdx.x;
  const int w  = t >> 6, l = t & 63, lr = l & 15, hi = l >> 4;
  const int bid = blockIdx.x;
  const int h   = (bid >> 3) & 3;
  const int g   = (bid & 7) | ((bid >> 5) << 3);
  const int it  = g % 96;
  const int js  = g / 96;
  const int i0 = it * 64;
  const int jbase = js * nsteps * 64;
  const int i_row = i0 + w*16 + lr;

  const float fsv  = fs2[(size_t)h*NN + i_row];
  const float TPh  = exp2f(-fsv - SHIFTC);
  const float EiNh = exp2f(-0.8f*fsv - SHIFTC);

  f32x4 acc[4];
#pragma unroll
  for (int q = 0; q < 4; ++q) acc[q] = (f32x4){0.f,0.f,0.f,0.f};
  float ls = 0.f;

  // adj staging slice for this thread (identical assignment to R8)
  const int r_ = t >> 2, ch_ = t & 3;
  const int* asrc = adj + (size_t)(i0 + r_)*NN + jbase + ch_*16;
  // wht staging slice: row h*64 + r_, j-chunk ch_*16 (32B per thread)
  const unsigned short* wsrc = wht + (size_t)(h*64 + r_)*NN + jbase + ch_*16;

  // prefetch step-0 adj into registers (16 VGPRs)
  i32x4 ajp[4];
#pragma unroll
  for (int q = 0; q < 4; ++q)
    ajp[q] = *reinterpret_cast<const i32x4*>(asrc + q*4);

  for (int st = 0; st < nsteps; ++st) {
    const int j0 = jbase + st*64;
    __syncthreads();
    { // stage WhT head-slice tile: 64 rows x 64 j, 32B per thread
      const unsigned short* src = wsrc + st*64;
      unsigned short* dst = swht + r_*72 + ch_*16;
      *reinterpret_cast<uint4*>(dst)     = *reinterpret_cast<const uint4*>(src);
      *reinterpret_cast<uint4*>(dst + 8) = *reinterpret_cast<const uint4*>(src + 8);
    }
    { // pack prefetched adj registers into smask bits
      unsigned int bits = 0u;
#pragma unroll
      for (int q = 0; q < 4; ++q) {
        bits |= (ajp[q].x != 0 ? 1u : 0u) << (q*4 + 0);
        bits |= (ajp[q].y != 0 ? 1u : 0u) << (q*4 + 1);
        bits |= (ajp[q].z != 0 ? 1u : 0u) << (q*4 + 2);
        bits |= (ajp[q].w != 0 ? 1u : 0u) << (q*4 + 3);
      }
      reinterpret_cast<unsigned short*>(smask)[r_*4 + ch_] = (unsigned short)bits;
    }
    if (t < 64) { // stage edp/edn head-slice (64 j)
      sedp[t] = edp[(size_t)h*NN + j0 + t];
      sedn[t] = edn[(size_t)h*NN + j0 + t];
    }
    __syncthreads();

    // issue next step's adj loads NOW (hide HBM latency under compute)
    if (st + 1 < nsteps) {
      const int* an = asrc + (st + 1)*64;
#pragma unroll
      for (int q = 0; q < 4; ++q)
        ajp[q] = *reinterpret_cast<const i32x4*>(an + q*4);
    }

    const unsigned int m0 = smask[(w*16 + lr)*2 + 0];
    const unsigned int m1 = smask[(w*16 + lr)*2 + 1];
    float maskf[16];
#pragma unroll
    for (int e = 0; e < 8; ++e) {
      maskf[e]     = ((m0 >> (8*hi + e)) & 1u) ? 1.f : 0.f;
      maskf[8 + e] = ((m1 >> (8*hi + e)) & 1u) ? 1.f : 0.f;
    }
    const f32x4 ep0 = *reinterpret_cast<const f32x4*>(&sedp[8*hi + 0]);
    const f32x4 ep1 = *reinterpret_cast<const f32x4*>(&sedp[8*hi + 4]);
    const f32x4 ep2 = *reinterpret_cast<const f32x4*>(&sedp[32 + 8*hi + 0]);
    const f32x4 ep3 = *reinterpret_cast<const f32x4*>(&sedp[32 + 8*hi + 4]);
    const f32x4 en0 = *reinterpret_cast<const f32x4*>(&sedn[8*hi + 0]);
    const f32x4 en1 = *reinterpret_cast<const f32x4*>(&sedn[8*hi + 4]);
    const f32x4 en2 = *reinterpret_cast<const f32x4*>(&sedn[32 + 8*hi + 0]);
    const f32x4 en3 = *reinterpret_cast<const f32x4*>(&sedn[32 + 8*hi + 4]);
    float p[16];
#pragma unroll
    for (int e = 0; e < 4; ++e) {
      p[e]      = maskf[e]      * (ep0[e] > TPh ? ep0[e] : EiNh * en0[e]);
      p[4 + e]  = maskf[4 + e]  * (ep1[e] > TPh ? ep1[e] : EiNh * en1[e]);
      p[8 + e]  = maskf[8 + e]  * (ep2[e] > TPh ? ep2[e] : EiNh * en2[e]);
      p[12 + e] = maskf[12 + e] * (ep3[e] > TPh ? ep3[e] : EiNh * en3[e]);
    }
    float lsh = 0.f;
#pragma unroll
    for (int e = 0; e < 16; ++e) lsh += p[e];
    ls += lsh;
    int4 aw0, aw1;
    asm("v_cvt_pk_bf16_f32 %0, %1, %2" : "=v"(aw0.x) : "v"(p[0]),  "v"(p[1]));
    asm("v_cvt_pk_bf16_f32 %0, %1, %2" : "=v"(aw0.y) : "v"(p[2]),  "v"(p[3]));
    asm("v_cvt_pk_bf16_f32 %0, %1, %2" : "=v"(aw0.z) : "v"(p[4]),  "v"(p[5]));
    asm("v_cvt_pk_bf16_f32 %0, %1, %2" : "=v"(aw0.w) : "v"(p[6]),  "v"(p[7]));
    asm("v_cvt_pk_bf16_f32 %0, %1, %2" : "=v"(aw1.x) : "v"(p[8]),  "v"(p[9]));
    asm("v_cvt_pk_bf16_f32 %0, %1, %2" : "=v"(aw1.y) : "v"(p[10]), "v"(p[11]));
    asm("v_cvt_pk_bf16_f32 %0, %1, %2" : "=v"(aw1.z) : "v"(p[12]), "v"(p[13]));
    asm("v_cvt_pk_bf16_f32 %0, %1, %2" : "=v"(aw1.w) : "v"(p[14]), "v"(p[15]));
    const short8 af0 = __builtin_bit_cast(short8, aw0);
    const short8 af1 = __builtin_bit_cast(short8, aw1);
#pragma unroll
    for (int nc = 0; nc < 4; ++nc) {
      const unsigned short* bp = swht + (size_t)(nc*16 + lr)*72 + 8*hi;
      const short8 b0 = *reinterpret_cast<const short8*>(bp);
      const short8 b1 = *reinterpret_cast<const short8*>(bp + 32);
      acc[nc] = __builtin_amdgcn_mfma_f32_16x16x32_bf16(af0, b0, acc[nc], 0, 0, 0);
      acc[nc] = __builtin_amdgcn_mfma_f32_16x16x32_bf16(af1, b1, acc[nc], 0, 0, 0);
    }
  }

  // reduce denominator across the 4 k-groups (lanes sharing lr)
  {
    float v = ls;
    v += __shfl_xor(v, 16, 64);
    v += __shfl_xor(v, 32, 64);
    ls = v;
  }
  if (hi == 0)
    lpart[((size_t)js*4 + h)*NN + i_row] = ls;
  // C/D layout: col = lane&15, row = 4*(lane>>4)+reg   [m89-verified]
#pragma unroll
  for (int nc = 0; nc < 4; ++nc)
#pragma unroll
    for (int rg = 0; rg < 4; ++rg) {
      const int irow = i0 + w*16 + 4*hi + rg;
      const int col  = h*64 + nc*16 + lr;
      apart[((size_t)js*NN + irow)*256 + col] = acc[nc][rg];
    }
}

// ---- kernel 4: combine partials ----
__global__ __launch_bounds__(256) void k_comb(const float* __restrict__ apart,
                                              const float* __restrict__ lpart,
                                              float* __restrict__ out,
                                              int jsplit){
  const int idx = blockIdx.x * 256 + threadIdx.x;
  const int i = idx >> 8, c = idx & 255, h = c >> 6;
  float num = 0.f, den = 0.f;
  for (int s = 0; s < jsplit; ++s) {
    num += apart[((size_t)s*NN + i)*256 + c];
    den += lpart[((size_t)s*4 + h)*NN + i];
  }
  out[idx] = (den > 0.f) ? (num / den) : 0.f;
}

extern "C" void kernel_launch(void* const* d_in, const int* in_sizes, int n_in,
                              void* d_out, int out_size, void* d_ws, size_t ws_size,
                              hipStream_t stream) {
  const float* x   = (const float*)d_in[0];
  const int*   adj = (const int*)d_in[1];
  const float* W   = (const float*)d_in[2];
  const float* a   = (const float*)d_in[3];
  float* out = (float*)d_out;
  char* ws = (char*)d_ws;

  size_t off = 0;
  unsigned short* wht = (unsigned short*)(ws + off); off += (size_t)256*NN*2;
  float* fs2 = (float*)(ws + off); off += (size_t)4*NN*4;
  float* edp = (float*)(ws + off); off += (size_t)4*NN*4;
  float* edn = (float*)(ws + off); off += (size_t)4*NN*4;

  int jsplit = 8;
  while (jsplit > 1 &&
         off + (size_t)jsplit*4*NN*4 + (size_t)jsplit*NN*256*4 > ws_size)
    jsplit >>= 1;

  float* lpart = (float*)(ws + off); off += (size_t)jsplit*4*NN*4;
  float* apart = (float*)(ws + off);

  const int nsteps = NN / (jsplit * 64);

  k_gemm<<<dim3(NN/16), dim3(256), 0, stream>>>(x, W, wht);
  k_f   <<<dim3(NN/64), dim3(256), 0, stream>>>(wht, a, fs2, edp, edn);
  k_attn<<<dim3(4*(NN/64)*jsplit), dim3(256), 0, stream>>>(adj, wht, fs2, edp, edn, apart, lpart, nsteps);
  k_comb<<<dim3((out_size + 255)/256), dim3(256), 0, stream>>>(apart, lpart, out, jsplit);
}

// Round 10
// 113.417 us; speedup vs baseline: 2.2894x; 1.0730x over previous
//
#include <hip/hip_runtime.h>

#define NN 6144
#define SHIFTC (12.0f*1.4426950408889634f)
#define LOG2E 1.4426950408889634f

typedef float f32x4 __attribute__((ext_vector_type(4)));
typedef short short8 __attribute__((ext_vector_type(8)));
typedef int   i32x4 __attribute__((ext_vector_type(4)));

__device__ __forceinline__ float bf2f(unsigned short u){
  return __uint_as_float(((unsigned int)u)<<16);
}
__device__ __forceinline__ unsigned short f2bf(float f){
  unsigned int x = __float_as_uint(f);
  x += 0x7fffu + ((x>>16)&1u);   // RNE
  return (unsigned short)(x>>16);
}

// ---- kernel 1: WhT bf16 [256][NN] = (x @ W)^T ----
__global__ __launch_bounds__(256) void k_gemm(const float* __restrict__ x,
                                              const float* __restrict__ W,
                                              unsigned short* __restrict__ wht){
  __shared__ float sx[16*256];
  const int t = threadIdx.x;
  const int i0 = blockIdx.x * 16;
  {
    const int r = t >> 4, kc = t & 15;
    const float* src = x + (size_t)(i0 + r)*256 + kc*16;
    float* dst = sx + r*256 + kc*16;
#pragma unroll
    for (int q = 0; q < 4; ++q)
      *reinterpret_cast<f32x4*>(dst + 4*q) = *reinterpret_cast<const f32x4*>(src + 4*q);
  }
  __syncthreads();
  float acc[16];
#pragma unroll
  for (int r = 0; r < 16; ++r) acc[r] = 0.f;
  for (int k = 0; k < 256; k += 4) {
    const float w0 = W[(size_t)(k+0)*256 + t];
    const float w1 = W[(size_t)(k+1)*256 + t];
    const float w2 = W[(size_t)(k+2)*256 + t];
    const float w3 = W[(size_t)(k+3)*256 + t];
#pragma unroll
    for (int r = 0; r < 16; ++r) {
      f32x4 xv = *reinterpret_cast<const f32x4*>(sx + r*256 + k);
      acc[r] = fmaf(xv.x, w0, acc[r]);
      acc[r] = fmaf(xv.y, w1, acc[r]);
      acc[r] = fmaf(xv.z, w2, acc[r]);
      acc[r] = fmaf(xv.w, w3, acc[r]);
    }
  }
  alignas(16) unsigned short buf[16];
#pragma unroll
  for (int r = 0; r < 16; ++r) buf[r] = f2bf(acc[r]);
  unsigned short* dst = wht + (size_t)t*NN + i0;
  *reinterpret_cast<uint4*>(dst)     = *reinterpret_cast<const uint4*>(buf);
  *reinterpret_cast<uint4*>(dst + 8) = *reinterpret_cast<const uint4*>(buf + 8);
}

// ---- kernel 2: per-node score factors ----
__global__ __launch_bounds__(256) void k_f(const unsigned short* __restrict__ wht,
                                           const float* __restrict__ a,
                                           float* __restrict__ fs2,
                                           float* __restrict__ edp,
                                           float* __restrict__ edn){
  __shared__ unsigned short sw[256*64];
  const int t = threadIdx.x;
  const int i0 = blockIdx.x * 64;
  {
    const unsigned short* src = wht + (size_t)t*NN + i0;
    unsigned short* dst = sw + t*64;
#pragma unroll
    for (int q = 0; q < 8; ++q)
      *reinterpret_cast<uint4*>(dst + q*8) = *reinterpret_cast<const uint4*>(src + q*8);
  }
  __syncthreads();
  const int ii = t & 63, h = t >> 6;
  float s_ = 0.f, d_ = 0.f;
#pragma unroll 16
  for (int d = 0; d < 64; ++d) {
    const float v = bf2f(sw[(h*64 + d)*64 + ii]);
    s_ = fmaf(v, a[d],      s_);
    d_ = fmaf(v, a[64 + d], d_);
  }
  const float fs2v = s_ * LOG2E;
  const float fd2v = d_ * LOG2E;
  fs2[(size_t)h*NN + i0 + ii] = fs2v;
  edp[(size_t)h*NN + i0 + ii] = exp2f(fd2v - SHIFTC);
  edn[(size_t)h*NN + i0 + ii] = exp2f(0.2f * fd2v);
}

// ---- kernel 3: fused masked-softmax attention, one head/block, dbuf 1-barrier ----
// grid: 4 heads x 96 i-tiles x jsplit.  h = (bid>>3)&3 keeps the h-quad of one
// (it,js) on the same XCD -> adj tile L2 reuse.  block: 256 = 4 waves.
__global__ __launch_bounds__(256) void k_attn(const int* __restrict__ adj,
                                              const unsigned short* __restrict__ wht,
                                              const float* __restrict__ fs2,
                                              const float* __restrict__ edp,
                                              const float* __restrict__ edn,
                                              float* __restrict__ apart,
                                              float* __restrict__ lpart,
                                              int nsteps){
  __shared__ unsigned short swht[2][64*72];   // double-buffered, padded rows
  __shared__ unsigned int   smask[2][128];
  __shared__ float          sedp[2][64];
  __shared__ float          sedn[2][64];
  const int t  = threadIdx.x;
  const int w  = t >> 6, l = t & 63, lr = l & 15, hi = l >> 4;
  const int bid = blockIdx.x;
  const int h   = (bid >> 3) & 3;
  const int g   = (bid & 7) | ((bid >> 5) << 3);
  const int it  = g % 96;
  const int js  = g / 96;
  const int i0 = it * 64;
  const int jbase = js * nsteps * 64;
  const int i_row = i0 + w*16 + lr;

  const float fsv  = fs2[(size_t)h*NN + i_row];
  const float EiNh = exp2f(-0.8f*fsv - SHIFTC);

  f32x4 acc[4];
#pragma unroll
  for (int q = 0; q < 4; ++q) acc[q] = (f32x4){0.f,0.f,0.f,0.f};
  float ls = 0.f;

  const int r_ = t >> 2, ch_ = t & 3;
  const int* asrc = adj + (size_t)(i0 + r_)*NN + jbase + ch_*16;
  const unsigned short* wsrc = wht + (size_t)(h*64 + r_)*NN + jbase + ch_*16;
  const float* pesrc = edp + (size_t)h*NN + jbase;
  const float* nesrc = edn + (size_t)h*NN + jbase;

  // ---- prologue: stage step 0 into buffer 0 ----
  {
    i32x4 aj[4];
#pragma unroll
    for (int q = 0; q < 4; ++q) aj[q] = *reinterpret_cast<const i32x4*>(asrc + q*4);
    const uint4 wv0 = *reinterpret_cast<const uint4*>(wsrc);
    const uint4 wv1 = *reinterpret_cast<const uint4*>(wsrc + 8);
    unsigned int bits = 0u;
#pragma unroll
    for (int q = 0; q < 4; ++q) {   // adj values are exactly 0/1 (randint(0,2))
      bits |= ((unsigned)aj[q].x) << (q*4 + 0);
      bits |= ((unsigned)aj[q].y) << (q*4 + 1);
      bits |= ((unsigned)aj[q].z) << (q*4 + 2);
      bits |= ((unsigned)aj[q].w) << (q*4 + 3);
    }
    unsigned short* dst = &swht[0][r_*72 + ch_*16];
    *reinterpret_cast<uint4*>(dst)     = wv0;
    *reinterpret_cast<uint4*>(dst + 8) = wv1;
    reinterpret_cast<unsigned short*>(smask[0])[r_*4 + ch_] = (unsigned short)bits;
    if (t < 64) { sedp[0][t] = pesrc[t]; sedn[0][t] = nesrc[t]; }
  }
  __syncthreads();

  for (int st = 0; st < nsteps; ++st) {
    const int cur = st & 1, nxt = cur ^ 1;
    const bool pf = (st + 1) < nsteps;   // block-uniform

    // ---- issue next step's loads into registers (hide under compute) ----
    i32x4 ajp[4]; uint4 wvp0, wvp1; float pep = 0.f, nep = 0.f;
    if (pf) {
      const int o = (st + 1) * 64;
#pragma unroll
      for (int q = 0; q < 4; ++q)
        ajp[q] = *reinterpret_cast<const i32x4*>(asrc + o + q*4);
      wvp0 = *reinterpret_cast<const uint4*>(wsrc + o);
      wvp1 = *reinterpret_cast<const uint4*>(wsrc + o + 8);
      if (t < 64) { pep = pesrc[o + t]; nep = nesrc[o + t]; }
    }

    // ---- compute current step from LDS buf[cur] ----
    const unsigned int m0 = smask[cur][(w*16 + lr)*2 + 0];
    const unsigned int m1 = smask[cur][(w*16 + lr)*2 + 1];
    float maskf[16];
#pragma unroll
    for (int e = 0; e < 8; ++e) {
      maskf[e]     = ((m0 >> (8*hi + e)) & 1u) ? 1.f : 0.f;
      maskf[8 + e] = ((m1 >> (8*hi + e)) & 1u) ? 1.f : 0.f;
    }
    const f32x4 ep0 = *reinterpret_cast<const f32x4*>(&sedp[cur][8*hi + 0]);
    const f32x4 ep1 = *reinterpret_cast<const f32x4*>(&sedp[cur][8*hi + 4]);
    const f32x4 ep2 = *reinterpret_cast<const f32x4*>(&sedp[cur][32 + 8*hi + 0]);
    const f32x4 ep3 = *reinterpret_cast<const f32x4*>(&sedp[cur][32 + 8*hi + 4]);
    const f32x4 en0 = *reinterpret_cast<const f32x4*>(&sedn[cur][8*hi + 0]);
    const f32x4 en1 = *reinterpret_cast<const f32x4*>(&sedn[cur][8*hi + 4]);
    const f32x4 en2 = *reinterpret_cast<const f32x4*>(&sedn[cur][32 + 8*hi + 0]);
    const f32x4 en3 = *reinterpret_cast<const f32x4*>(&sedn[cur][32 + 8*hi + 4]);
    float p[16];
    // p = mask * max(edp_j, EiN_i*edn_j)  — exact LeakyReLU-softmax factorization:
    // edp/(EiN*edn) = 2^(0.8*s), so the larger branch is the correct one.
#pragma unroll
    for (int e = 0; e < 4; ++e) {
      p[e]      = maskf[e]      * fmaxf(ep0[e], EiNh * en0[e]);
      p[4 + e]  = maskf[4 + e]  * fmaxf(ep1[e], EiNh * en1[e]);
      p[8 + e]  = maskf[8 + e]  * fmaxf(ep2[e], EiNh * en2[e]);
      p[12 + e] = maskf[12 + e] * fmaxf(ep3[e], EiNh * en3[e]);
    }
    float lsh = 0.f;
#pragma unroll
    for (int e = 0; e < 16; ++e) lsh += p[e];
    ls += lsh;
    int4 aw0, aw1;
    asm("v_cvt_pk_bf16_f32 %0, %1, %2" : "=v"(aw0.x) : "v"(p[0]),  "v"(p[1]));
    asm("v_cvt_pk_bf16_f32 %0, %1, %2" : "=v"(aw0.y) : "v"(p[2]),  "v"(p[3]));
    asm("v_cvt_pk_bf16_f32 %0, %1, %2" : "=v"(aw0.z) : "v"(p[4]),  "v"(p[5]));
    asm("v_cvt_pk_bf16_f32 %0, %1, %2" : "=v"(aw0.w) : "v"(p[6]),  "v"(p[7]));
    asm("v_cvt_pk_bf16_f32 %0, %1, %2" : "=v"(aw1.x) : "v"(p[8]),  "v"(p[9]));
    asm("v_cvt_pk_bf16_f32 %0, %1, %2" : "=v"(aw1.y) : "v"(p[10]), "v"(p[11]));
    asm("v_cvt_pk_bf16_f32 %0, %1, %2" : "=v"(aw1.z) : "v"(p[12]), "v"(p[13]));
    asm("v_cvt_pk_bf16_f32 %0, %1, %2" : "=v"(aw1.w) : "v"(p[14]), "v"(p[15]));
    const short8 af0 = __builtin_bit_cast(short8, aw0);
    const short8 af1 = __builtin_bit_cast(short8, aw1);
#pragma unroll
    for (int nc = 0; nc < 4; ++nc) {
      const unsigned short* bp = &swht[cur][(nc*16 + lr)*72 + 8*hi];
      const short8 b0 = *reinterpret_cast<const short8*>(bp);
      const short8 b1 = *reinterpret_cast<const short8*>(bp + 32);
      acc[nc] = __builtin_amdgcn_mfma_f32_16x16x32_bf16(af0, b0, acc[nc], 0, 0, 0);
      acc[nc] = __builtin_amdgcn_mfma_f32_16x16x32_bf16(af1, b1, acc[nc], 0, 0, 0);
    }

    // ---- commit prefetched step into buf[nxt] (buf[nxt] readers finished
    //      before the PREVIOUS barrier -> no extra barrier needed) ----
    if (pf) {
      unsigned int bits = 0u;
#pragma unroll
      for (int q = 0; q < 4; ++q) {
        bits |= ((unsigned)ajp[q].x) << (q*4 + 0);
        bits |= ((unsigned)ajp[q].y) << (q*4 + 1);
        bits |= ((unsigned)ajp[q].z) << (q*4 + 2);
        bits |= ((unsigned)ajp[q].w) << (q*4 + 3);
      }
      unsigned short* dst = &swht[nxt][r_*72 + ch_*16];
      *reinterpret_cast<uint4*>(dst)     = wvp0;
      *reinterpret_cast<uint4*>(dst + 8) = wvp1;
      reinterpret_cast<unsigned short*>(smask[nxt])[r_*4 + ch_] = (unsigned short)bits;
      if (t < 64) { sedp[nxt][t] = pep; sedn[nxt][t] = nep; }
    }
    __syncthreads();   // one barrier per step
  }

  // reduce denominator across the 4 k-groups (lanes sharing lr)
  {
    float v = ls;
    v += __shfl_xor(v, 16, 64);
    v += __shfl_xor(v, 32, 64);
    ls = v;
  }
  if (hi == 0)
    lpart[((size_t)js*4 + h)*NN + i_row] = ls;
  // C/D layout: col = lane&15, row = 4*(lane>>4)+reg   [m89-verified]
#pragma unroll
  for (int nc = 0; nc < 4; ++nc)
#pragma unroll
    for (int rg = 0; rg < 4; ++rg) {
      const int irow = i0 + w*16 + 4*hi + rg;
      const int col  = h*64 + nc*16 + lr;
      apart[((size_t)js*NN + irow)*256 + col] = acc[nc][rg];
    }
}

// ---- kernel 4: combine partials ----
__global__ __launch_bounds__(256) void k_comb(const float* __restrict__ apart,
                                              const float* __restrict__ lpart,
                                              float* __restrict__ out,
                                              int jsplit){
  const int idx = blockIdx.x * 256 + threadIdx.x;
  const int i = idx >> 8, c = idx & 255, h = c >> 6;
  float num = 0.f, den = 0.f;
  for (int s = 0; s < jsplit; ++s) {
    num += apart[((size_t)s*NN + i)*256 + c];
    den += lpart[((size_t)s*4 + h)*NN + i];
  }
  out[idx] = (den > 0.f) ? (num / den) : 0.f;
}

extern "C" void kernel_launch(void* const* d_in, const int* in_sizes, int n_in,
                              void* d_out, int out_size, void* d_ws, size_t ws_size,
                              hipStream_t stream) {
  const float* x   = (const float*)d_in[0];
  const int*   adj = (const int*)d_in[1];
  const float* W   = (const float*)d_in[2];
  const float* a   = (const float*)d_in[3];
  float* out = (float*)d_out;
  char* ws = (char*)d_ws;

  size_t off = 0;
  unsigned short* wht = (unsigned short*)(ws + off); off += (size_t)256*NN*2;
  float* fs2 = (float*)(ws + off); off += (size_t)4*NN*4;
  float* edp = (float*)(ws + off); off += (size_t)4*NN*4;
  float* edn = (float*)(ws + off); off += (size_t)4*NN*4;

  int jsplit = 8;
  while (jsplit > 1 &&
         off + (size_t)jsplit*4*NN*4 + (size_t)jsplit*NN*256*4 > ws_size)
    jsplit >>= 1;

  float* lpart = (float*)(ws + off); off += (size_t)jsplit*4*NN*4;
  float* apart = (float*)(ws + off);

  const int nsteps = NN / (jsplit * 64);

  k_gemm<<<dim3(NN/16), dim3(256), 0, stream>>>(x, W, wht);
  k_f   <<<dim3(NN/64), dim3(256), 0, stream>>>(wht, a, fs2, edp, edn);
  k_attn<<<dim3(4*(NN/64)*jsplit), dim3(256), 0, stream>>>(adj, wht, fs2, edp, edn, apart, lpart, nsteps);
  k_comb<<<dim3((out_size + 255)/256), dim3(256), 0, stream>>>(apart, lpart, out, jsplit);
}